// Round 9
// baseline (219.558 us; speedup 1.0000x reference)
//
#include <hip/hip_runtime.h>
#include <hip/hip_bf16.h>

#define N_NODES 100000
#define N_EDGES 1600000
#define D 64
#define NEG_SLOPE 0.2f

#define BSHIFT 8                                   // bucket = dst >> 8
#define BNODES 256                                 // nodes per bucket
#define NBUCK ((N_NODES + BNODES - 1) >> BSHIFT)   // 391
#define BUCKET_CAP 4672    // mean 4096, sigma ~64 -> +9 sigma headroom
#define P1_EPB 4096        // edges per binning block
#define P1_T 512
#define P1_IT (P1_EPB / P1_T)                      // 8 edges/thread

// ---------------------------------------------------------------------------
// Pass 1: bin edges by coarse dst bucket, LDS-staged so ALL global writes are
// coalesced runs (direct scatter wrote 100 MB of dirty partial lines for a
// 12.8 MB array -- write-line-granularity bound). Entry: {x = (src<<15)|wcode
// (bf16 weight, sign dropped), y = dst}. 391 buckets: ~10 edges/LDS-counter
// (low atomic contention). Both scans parallel (serial tid0 loop removed).
// segment_max skipped: softmax is shift-invariant and |e| <= |a0|+|a1| is
// tiny, so exp() cannot overflow -- identical math to the reference.
// ---------------------------------------------------------------------------
__global__ __launch_bounds__(P1_T) void binning_kernel(
    const float2* __restrict__ rel, const float* __restrict__ attn_e,
    const int* __restrict__ src, const int* __restrict__ dst,
    int* __restrict__ bucket_cursor, uint2* __restrict__ binned)
{
    __shared__ uint2 staged1[P1_EPB];   // arrival order      (32 KB)
    __shared__ uint2 staged2[P1_EPB];   // bucket-sorted      (32 KB)
    __shared__ int cnt[NBUCK];
    __shared__ int excl[NBUCK];
    __shared__ int chunkbase[NBUCK];
    __shared__ int scanbuf[P1_T];

    int tid = threadIdx.x;
    int e0 = blockIdx.x * P1_EPB;
    int n = min(P1_EPB, N_EDGES - e0);

    for (int b = tid; b < NBUCK; b += P1_T) cnt[b] = 0;
    __syncthreads();

    float a0 = attn_e[0], a1 = attn_e[1];

    int myslot[P1_IT];                  // fixed-index -> stays in VGPRs
    #pragma unroll
    for (int j = 0; j < P1_IT; ++j) {
        int i = tid + j * P1_T;
        if (i < n) {
            int e = e0 + i;
            float2 r = rel[e];
            float sc = r.x * a0 + r.y * a1;
            sc = (sc > 0.f) ? sc : NEG_SLOPE * sc;
            float ev = __expf(sc);
            unsigned u = __float_as_uint(ev) + 0x8000u;     // RNE to bf16
            unsigned wcode = (u >> 16) & 0x7FFFu;           // drop sign (ev>0)
            unsigned s = (unsigned)src[e];
            unsigned d = (unsigned)dst[e];
            staged1[i] = make_uint2((s << 15) | wcode, d);
            myslot[j] = atomicAdd(&cnt[d >> BSHIFT], 1);    // local ticket
        }
    }
    __syncthreads();
    {   // parallel exclusive scan of cnt[NBUCK] (NBUCK <= P1_T)
        int c = (tid < NBUCK) ? cnt[tid] : 0;
        scanbuf[tid] = c;
        __syncthreads();
        for (int d = 1; d < P1_T; d <<= 1) {
            int u = (tid >= d) ? scanbuf[tid - d] : 0;
            __syncthreads();
            scanbuf[tid] += u;
            __syncthreads();
        }
        if (tid < NBUCK) excl[tid] = scanbuf[tid] - c;
    }
    __syncthreads();
    #pragma unroll
    for (int j = 0; j < P1_IT; ++j) {   // LDS scatter into bucket order
        int i = tid + j * P1_T;
        if (i < n) {
            uint2 v = staged1[i];
            staged2[excl[v.y >> BSHIFT] + myslot[j]] = v;
        }
    }
    if (tid < NBUCK)                    // reserve contiguous global chunks
        chunkbase[tid] = atomicAdd(&bucket_cursor[tid], cnt[tid]);
    __syncthreads();
    for (int i = tid; i < n; i += P1_T) {  // coalesced runs per bucket chunk
        uint2 v = staged2[i];
        int b = (int)(v.y >> BSHIFT);
        binned[(size_t)b * BUCKET_CAP + chunkbase[b] + (i - excl[b])] = v;
    }
}

// ---------------------------------------------------------------------------
// Pass 2: one block per bucket (391 blocks -- round-8's 98 underused the
// grid). LDS histogram (256 bins) -> parallel scans -> write offsets -> LDS
// scatter of packed values -> coalesced flush into the bucket's CSR range.
// ---------------------------------------------------------------------------
__global__ __launch_bounds__(512) void csr_kernel(
    const int* __restrict__ bucket_cursor, const uint2* __restrict__ binned,
    int* __restrict__ offsets, unsigned* __restrict__ edata)
{
    __shared__ unsigned vals[BUCKET_CAP];   // 18.7 KB
    __shared__ int hist[BNODES];
    __shared__ int nexcl[BNODES];
    __shared__ int cur[BNODES];
    __shared__ int scanbuf[512];

    int b = blockIdx.x;
    int tid = threadIdx.x;

    if (tid < BNODES) { hist[tid] = 0; cur[tid] = 0; }
    // parallel exclusive scan of bucket counts -> this bucket's global base
    int c = (tid < NBUCK) ? bucket_cursor[tid] : 0;
    scanbuf[tid] = c;
    __syncthreads();
    for (int d = 1; d < 512; d <<= 1) {
        int u = (tid >= d) ? scanbuf[tid - d] : 0;
        __syncthreads();
        scanbuf[tid] += u;
        __syncthreads();
    }
    int base = (b == 0) ? 0 : scanbuf[b - 1];
    int count = scanbuf[b] - base;
    const uint2* bin = binned + (size_t)b * BUCKET_CAP;

    for (int i = tid; i < count; i += 512)
        atomicAdd(&hist[bin[i].y & (BNODES - 1)], 1);
    __syncthreads();

    // exclusive scan over 256 bins (first 256 threads; all hit barriers)
    int h = (tid < BNODES) ? hist[tid] : 0;
    scanbuf[tid] = (tid < BNODES) ? h : 0;
    __syncthreads();
    for (int d = 1; d < BNODES; d <<= 1) {
        int u = (tid >= d) ? scanbuf[tid - d] : 0;
        __syncthreads();
        scanbuf[tid] += u;
        __syncthreads();
    }
    if (tid < BNODES) nexcl[tid] = scanbuf[tid] - h;
    __syncthreads();

    int node = (b << BSHIFT) + tid;
    if (tid < BNODES && node < N_NODES) offsets[node] = base + nexcl[tid];
    if (b == NBUCK - 1 && tid == 0) offsets[N_NODES] = N_EDGES;

    for (int i = tid; i < count; i += 512) {      // LDS scatter
        uint2 e = bin[i];
        int d = e.y & (BNODES - 1);
        int t = atomicAdd(&cur[d], 1);
        vals[nexcl[d] + t] = e.x;
    }
    __syncthreads();
    for (int i = tid; i < count; i += 512)        // coalesced flush
        edata[base + i] = vals[i];
}

// ---------------------------------------------------------------------------
// FUSED GEMM: 512 threads = 8 waves; waves 0-3 self, 4-7 neigh. Each lane
// reads its own contiguous 256B weight column straight from global into
// 16 float4 REGISTERS (W is 16 KB, L1/L2-hot, same for every block -- no LDS
// staging). Round-8 version let the compiler demote w[] to per-iteration
// LDS reads (VGPR_Count=44, LDS-issue-bound at 48us); __launch_bounds__(512,2)
// gives the allocator a 2-waves/EU budget so the registers stick.
// ---------------------------------------------------------------------------
__global__ __launch_bounds__(512, 2) void gemm_fused_kernel(
    const float* __restrict__ feat, const float* __restrict__ W_self,
    const float* __restrict__ W_neigh, const float* __restrict__ b_self,
    const float* __restrict__ b_neigh, float* __restrict__ out,
    __hip_bfloat16* __restrict__ g)
{
    __shared__ float fs[64 * D];               // 64 feat rows, 16 KB
    int tid = threadIdx.x;
    {
        long base4 = (long)blockIdx.x * 1024;  // float4 index
        const float4* f4 = (const float4*)feat;
        float4* s4 = (float4*)fs;
        #pragma unroll
        for (int i = 0; i < 2; ++i) {
            int idx = tid + i * 512;
            if (base4 + idx < (long)N_NODES * D / 4) s4[idx] = f4[base4 + idx];
        }
    }

    int lane = tid & 63;
    int wave = tid >> 6;
    int m = wave >> 2;                         // 0 = self, 1 = neigh
    int sw = wave & 3;                         // sub-wave within matrix
    const float4* Wrow = (const float4*)(((m == 0) ? W_self : W_neigh)
                                         + (size_t)lane * D);
    float4 w4[16];                             // 64 VGPRs of weights
    #pragma unroll
    for (int k4 = 0; k4 < 16; ++k4) w4[k4] = Wrow[k4];
    float bias = (m == 0) ? (b_self[lane] + b_neigh[lane]) : 0.f;
    __syncthreads();

    int r0 = blockIdx.x * 64 + sw * 16;        // 16 rows per wave
    #pragma unroll 1
    for (int rr = 0; rr < 16; ++rr) {
        int r = r0 + rr;
        if (r >= N_NODES) break;
        const float4* frow = (const float4*)(fs + (sw * 16 + rr) * D);
        float acc = 0.f;
        #pragma unroll
        for (int k4 = 0; k4 < 16; ++k4) {
            float4 f = frow[k4];               // LDS broadcast (same addr)
            acc += f.x * w4[k4].x + f.y * w4[k4].y
                 + f.z * w4[k4].z + f.w * w4[k4].w;
        }
        if (m == 0) out[(size_t)r * D + lane] = acc + bias;
        else        g[(size_t)r * D + lane] = __float2bfloat16(acc);
    }
}

// ---------------------------------------------------------------------------
// Aggregation: one wave per node, 8 edges per iteration (2 independent row
// gathers in flight per 16-lane group). Lane = 16*q + t: group q handles
// edges i+q, i+4+q; lane t covers features 4t..4t+3 via uint2 (4 bf16).
// Zero atomics; denominator computed in-wave.
// ---------------------------------------------------------------------------
__global__ __launch_bounds__(256) void aggregate_kernel(
    const uint* __restrict__ g32, const unsigned* __restrict__ edata,
    const int* __restrict__ offsets, float* __restrict__ out)
{
    int v = blockIdx.x * 4 + (threadIdx.x >> 6);   // 25000*4 == N exactly
    int lane = threadIdx.x & 63;
    int q = lane >> 4;                 // edge group
    int t = lane & 15;                 // feature quad: features 4t..4t+3
    int lo = offsets[v], hi = offsets[v + 1];
    float4 acc = make_float4(0.f, 0.f, 0.f, 0.f);
    float sum = 0.f;

    for (int i = lo; i < hi; i += 8) {
        int e0 = i + q;
        int e1 = i + 4 + q;
        int ec0 = (e0 < hi) ? e0 : hi - 1;         // in-bounds (loop => hi>lo)
        int ec1 = (e1 < hi) ? e1 : hi - 1;
        unsigned p0 = edata[ec0];                  // coalesced, L2-hot
        unsigned p1 = edata[ec1];
        float w0 = (e0 < hi) ? __uint_as_float((p0 & 0x7FFFu) << 16) : 0.f;
        float w1 = (e1 < hi) ? __uint_as_float((p1 & 0x7FFFu) << 16) : 0.f;
        const uint2* r0 = (const uint2*)(g32 + (size_t)(p0 >> 15) * (D / 2));
        const uint2* r1 = (const uint2*)(g32 + (size_t)(p1 >> 15) * (D / 2));
        uint2 u0 = r0[t];                          // 2 gathers in flight
        uint2 u1 = r1[t];
        acc.x += w0 * __uint_as_float(u0.x << 16);
        acc.y += w0 * __uint_as_float(u0.x & 0xFFFF0000u);
        acc.z += w0 * __uint_as_float(u0.y << 16);
        acc.w += w0 * __uint_as_float(u0.y & 0xFFFF0000u);
        sum += w0;
        acc.x += w1 * __uint_as_float(u1.x << 16);
        acc.y += w1 * __uint_as_float(u1.x & 0xFFFF0000u);
        acc.z += w1 * __uint_as_float(u1.y << 16);
        acc.w += w1 * __uint_as_float(u1.y & 0xFFFF0000u);
        sum += w1;
    }
    // combine the 4 groups (each lane t holds partials for feats 4t..4t+3)
    #pragma unroll
    for (int mm = 16; mm <= 32; mm <<= 1) {
        acc.x += __shfl_xor(acc.x, mm, 64);
        acc.y += __shfl_xor(acc.y, mm, 64);
        acc.z += __shfl_xor(acc.z, mm, 64);
        acc.w += __shfl_xor(acc.w, mm, 64);
        sum   += __shfl_xor(sum,   mm, 64);
    }
    if (hi > lo && q == 0) {                       // 16 lanes: float4 each
        float inv = 1.f / sum;
        float4* orow = (float4*)(out + (size_t)v * D);
        float4 c = orow[t];
        c.x += acc.x * inv; c.y += acc.y * inv;
        c.z += acc.z * inv; c.w += acc.w * inv;
        orow[t] = c;
    }
    // zero-degree nodes: reference gives h_neigh = 0 -> out keeps self part
}

// ---------------------------------------------------------------------------
extern "C" void kernel_launch(void* const* d_in, const int* in_sizes, int n_in,
                              void* d_out, int out_size, void* d_ws, size_t ws_size,
                              hipStream_t stream) {
    const float* feat    = (const float*)d_in[0];
    const float* rel     = (const float*)d_in[1];
    const float* W_self  = (const float*)d_in[2];
    const float* b_self  = (const float*)d_in[3];
    const float* W_neigh = (const float*)d_in[4];
    const float* b_neigh = (const float*)d_in[5];
    const float* attn_e  = (const float*)d_in[6];
    const int*   src     = (const int*)d_in[7];
    const int*   dst     = (const int*)d_in[8];
    float* out = (float*)d_out;

    // workspace layout (~34 MB)
    uint2* binned = (uint2*)d_ws;                               // 14.6 MB
    __hip_bfloat16* g = (__hip_bfloat16*)(binned + (size_t)NBUCK * BUCKET_CAP); // 12.8 MB
    unsigned* edata = (unsigned*)((char*)g + (size_t)N_NODES * D * 2);  // 6.4 MB
    int* offsets = (int*)(edata + N_EDGES);                     // [N+1]
    int* bucket_cursor = offsets + N_NODES + 1;                 // [NBUCK]

    hipMemsetAsync(bucket_cursor, 0, NBUCK * sizeof(int), stream);

    binning_kernel<<<(N_EDGES + P1_EPB - 1) / P1_EPB, P1_T, 0, stream>>>(
        (const float2*)rel, attn_e, src, dst, bucket_cursor, binned);
    csr_kernel<<<NBUCK, 512, 0, stream>>>(
        bucket_cursor, binned, offsets, edata);
    gemm_fused_kernel<<<(N_NODES + 63) / 64, 512, 0, stream>>>(
        feat, W_self, W_neigh, b_self, b_neigh, out, g);
    aggregate_kernel<<<N_NODES / 4, 256, 0, stream>>>(
        (const uint*)g, edata, offsets, out);
}

// Round 10
// 218.410 us; speedup vs baseline: 1.0053x; 1.0053x over previous
//
#include <hip/hip_runtime.h>
#include <hip/hip_bf16.h>

#define N_NODES 100000
#define N_EDGES 1600000
#define D 64
#define NEG_SLOPE 0.2f

#define BSHIFT 8                                   // bucket = dst >> 8
#define BNODES 256                                 // nodes per bucket
#define NBUCK ((N_NODES + BNODES - 1) >> BSHIFT)   // 391
#define BUCKET_CAP 4672    // mean 4096, sigma ~64 -> +9 sigma headroom
#define P1_EPB 4096        // edges per binning block
#define P1_T 512
#define P1_IT (P1_EPB / P1_T)                      // 8 edges/thread

// ---------------------------------------------------------------------------
// Pass 1: bin edges by coarse dst bucket, LDS-staged so ALL global writes are
// coalesced runs. Entry: {x = (src<<15)|wcode (bf16 weight, sign dropped),
// y = dst}. Bucket-count scan done by a single wave with shfl_up (the
// round-9 full-block Hillis-Steele cost 18 barriers on 512 threads).
// segment_max skipped: softmax is shift-invariant and |e| <= |a0|+|a1| is
// tiny, so exp() cannot overflow -- identical math to the reference.
// ---------------------------------------------------------------------------
__global__ __launch_bounds__(P1_T) void binning_kernel(
    const float2* __restrict__ rel, const float* __restrict__ attn_e,
    const int* __restrict__ src, const int* __restrict__ dst,
    int* __restrict__ bucket_cursor, uint2* __restrict__ binned)
{
    __shared__ uint2 staged1[P1_EPB];   // arrival order      (32 KB)
    __shared__ uint2 staged2[P1_EPB];   // bucket-sorted      (32 KB)
    __shared__ int cnt[NBUCK];
    __shared__ int excl[NBUCK];
    __shared__ int chunkbase[NBUCK];

    int tid = threadIdx.x;
    int e0 = blockIdx.x * P1_EPB;
    int n = min(P1_EPB, N_EDGES - e0);

    for (int b = tid; b < NBUCK; b += P1_T) cnt[b] = 0;
    __syncthreads();

    float a0 = attn_e[0], a1 = attn_e[1];

    int myslot[P1_IT];                  // fixed-index -> stays in VGPRs
    #pragma unroll
    for (int j = 0; j < P1_IT; ++j) {
        int i = tid + j * P1_T;
        if (i < n) {
            int e = e0 + i;
            float2 r = rel[e];
            float sc = r.x * a0 + r.y * a1;
            sc = (sc > 0.f) ? sc : NEG_SLOPE * sc;
            float ev = __expf(sc);
            unsigned u = __float_as_uint(ev) + 0x8000u;     // RNE to bf16
            unsigned wcode = (u >> 16) & 0x7FFFu;           // drop sign (ev>0)
            unsigned s = (unsigned)src[e];
            unsigned d = (unsigned)dst[e];
            staged1[i] = make_uint2((s << 15) | wcode, d);
            myslot[j] = atomicAdd(&cnt[d >> BSHIFT], 1);    // local ticket
        }
    }
    __syncthreads();
    if (tid < 64) {                     // single-wave scan of 391 counts
        int run = 0;
        for (int base = 0; base < NBUCK; base += 64) {
            int idx = base + tid;
            int c = (idx < NBUCK) ? cnt[idx] : 0;
            int x = c;
            #pragma unroll
            for (int o = 1; o < 64; o <<= 1) {
                int y = __shfl_up(x, o, 64);
                if (tid >= o) x += y;
            }
            if (idx < NBUCK) excl[idx] = run + x - c;
            run += __shfl(x, 63, 64);
        }
    }
    __syncthreads();
    #pragma unroll
    for (int j = 0; j < P1_IT; ++j) {   // LDS scatter into bucket order
        int i = tid + j * P1_T;
        if (i < n) {
            uint2 v = staged1[i];
            staged2[excl[v.y >> BSHIFT] + myslot[j]] = v;
        }
    }
    if (tid < NBUCK)                    // reserve contiguous global chunks
        chunkbase[tid] = atomicAdd(&bucket_cursor[tid], cnt[tid]);
    __syncthreads();
    for (int i = tid; i < n; i += P1_T) {  // coalesced runs per bucket chunk
        uint2 v = staged2[i];
        int b = (int)(v.y >> BSHIFT);
        binned[(size_t)b * BUCKET_CAP + chunkbase[b] + (i - excl[b])] = v;
    }
}

// ---------------------------------------------------------------------------
// Tiny 1-block scan: bucket_base = exclusive prefix of bucket counts.
// (Round-9 csr re-ran this scan in every one of 391 blocks.)
// ---------------------------------------------------------------------------
__global__ __launch_bounds__(512) void bucket_scan_kernel(
    const int* __restrict__ bucket_cursor, int* __restrict__ bucket_base)
{
    __shared__ int sb[512];
    int t = threadIdx.x;
    int c = (t < NBUCK) ? bucket_cursor[t] : 0;
    sb[t] = c;
    __syncthreads();
    for (int d = 1; d < 512; d <<= 1) {
        int u = (t >= d) ? sb[t - d] : 0;
        __syncthreads();
        sb[t] += u;
        __syncthreads();
    }
    if (t < NBUCK) bucket_base[t] = sb[t] - c;
}

// ---------------------------------------------------------------------------
// Pass 2: one block per bucket. LDS histogram (256 bins) -> scan -> write
// offsets -> LDS scatter of packed values -> coalesced flush into CSR range.
// ---------------------------------------------------------------------------
__global__ __launch_bounds__(512) void csr_kernel(
    const int* __restrict__ bucket_cursor, const int* __restrict__ bucket_base,
    const uint2* __restrict__ binned, int* __restrict__ offsets,
    unsigned* __restrict__ edata)
{
    __shared__ unsigned vals[BUCKET_CAP];   // 18.7 KB
    __shared__ int hist[BNODES];
    __shared__ int nexcl[BNODES];
    __shared__ int cur[BNODES];
    __shared__ int scanbuf[256];

    int b = blockIdx.x;
    int tid = threadIdx.x;

    if (tid < BNODES) { hist[tid] = 0; cur[tid] = 0; }
    __syncthreads();
    int base = bucket_base[b];
    int count = bucket_cursor[b];
    const uint2* bin = binned + (size_t)b * BUCKET_CAP;

    for (int i = tid; i < count; i += 512)
        atomicAdd(&hist[bin[i].y & (BNODES - 1)], 1);
    __syncthreads();

    // exclusive scan over 256 bins (first 256 threads; all hit barriers)
    int h = (tid < BNODES) ? hist[tid] : 0;
    if (tid < BNODES) scanbuf[tid] = h;
    __syncthreads();
    for (int d = 1; d < BNODES; d <<= 1) {
        int u = (tid >= d && tid < BNODES) ? scanbuf[tid - d] : 0;
        __syncthreads();
        if (tid < BNODES) scanbuf[tid] += u;
        __syncthreads();
    }
    if (tid < BNODES) nexcl[tid] = scanbuf[tid] - h;
    __syncthreads();

    int node = (b << BSHIFT) + tid;
    if (tid < BNODES && node < N_NODES) offsets[node] = base + nexcl[tid];
    if (b == NBUCK - 1 && tid == 0) offsets[N_NODES] = N_EDGES;

    for (int i = tid; i < count; i += 512) {      // LDS scatter
        uint2 e = bin[i];
        int d = e.y & (BNODES - 1);
        int t = atomicAdd(&cur[d], 1);
        vals[nexcl[d] + t] = e.x;
    }
    __syncthreads();
    for (int i = tid; i < count; i += 512)        // coalesced flush
        edata[base + i] = vals[i];
}

// ---------------------------------------------------------------------------
// FUSED GEMM: 512 threads = 8 waves; waves 0-3 self, 4-7 neigh. Lane o's
// 256B weight column lives in 16 NAMED float4 locals -- rounds 8/9 proved
// the compiler refuses to register-promote a 16-element ARRAY of
// loop-invariant loads (VGPR_Count stayed 44, loads rematerialized per row).
// Named scalars + loads hoisted before __syncthreads force residency.
// Success tell: VGPR_Count >= ~100.
// ---------------------------------------------------------------------------
__global__ __launch_bounds__(512, 2) void gemm_fused_kernel(
    const float* __restrict__ feat, const float* __restrict__ W_self,
    const float* __restrict__ W_neigh, const float* __restrict__ b_self,
    const float* __restrict__ b_neigh, float* __restrict__ out,
    __hip_bfloat16* __restrict__ g)
{
    __shared__ float fs[64 * D];               // 64 feat rows, 16 KB
    int tid = threadIdx.x;
    {
        long base4 = (long)blockIdx.x * 1024;  // float4 index
        const float4* f4 = (const float4*)feat;
        float4* s4 = (float4*)fs;
        #pragma unroll
        for (int i = 0; i < 2; ++i) {
            int idx = tid + i * 512;
            if (base4 + idx < (long)N_NODES * D / 4) s4[idx] = f4[base4 + idx];
        }
    }

    int lane = tid & 63;
    int wave = tid >> 6;
    int m = wave >> 2;                         // 0 = self, 1 = neigh
    int sw = wave & 3;                         // sub-wave within matrix
    const float4* Wrow = (const float4*)(((m == 0) ? W_self : W_neigh)
                                         + (size_t)lane * D);
    float4 w0  = Wrow[0],  w1  = Wrow[1],  w2  = Wrow[2],  w3  = Wrow[3];
    float4 w4  = Wrow[4],  w5  = Wrow[5],  w6  = Wrow[6],  w7  = Wrow[7];
    float4 w8  = Wrow[8],  w9  = Wrow[9],  w10 = Wrow[10], w11 = Wrow[11];
    float4 w12 = Wrow[12], w13 = Wrow[13], w14 = Wrow[14], w15 = Wrow[15];
    float bias = (m == 0) ? (b_self[lane] + b_neigh[lane]) : 0.f;
    __syncthreads();

    int r0 = blockIdx.x * 64 + sw * 16;        // 16 rows per wave
    #pragma unroll 1
    for (int rr = 0; rr < 16; ++rr) {
        const float4* frow = (const float4*)(fs + (sw * 16 + rr) * D);
        float acc = 0.f;
        float4 f;
#define STEP(i, W) f = frow[i]; \
        acc += f.x * W.x + f.y * W.y + f.z * W.z + f.w * W.w;
        STEP(0, w0)   STEP(1, w1)   STEP(2, w2)   STEP(3, w3)
        STEP(4, w4)   STEP(5, w5)   STEP(6, w6)   STEP(7, w7)
        STEP(8, w8)   STEP(9, w9)   STEP(10, w10) STEP(11, w11)
        STEP(12, w12) STEP(13, w13) STEP(14, w14) STEP(15, w15)
#undef STEP
        int r = r0 + rr;
        if (r < N_NODES) {
            if (m == 0) out[(size_t)r * D + lane] = acc + bias;
            else        g[(size_t)r * D + lane] = __float2bfloat16(acc);
        }
    }
}

// ---------------------------------------------------------------------------
// Aggregation: one wave per node, 8 edges per iteration (2 independent row
// gathers in flight per 16-lane group). Lane = 16*q + t: group q handles
// edges i+q, i+4+q; lane t covers features 4t..4t+3 via uint2 (4 bf16).
// Zero atomics; denominator computed in-wave.
// ---------------------------------------------------------------------------
__global__ __launch_bounds__(256) void aggregate_kernel(
    const uint* __restrict__ g32, const unsigned* __restrict__ edata,
    const int* __restrict__ offsets, float* __restrict__ out)
{
    int v = blockIdx.x * 4 + (threadIdx.x >> 6);   // 25000*4 == N exactly
    int lane = threadIdx.x & 63;
    int q = lane >> 4;                 // edge group
    int t = lane & 15;                 // feature quad: features 4t..4t+3
    int lo = offsets[v], hi = offsets[v + 1];
    float4 acc = make_float4(0.f, 0.f, 0.f, 0.f);
    float sum = 0.f;

    for (int i = lo; i < hi; i += 8) {
        int e0 = i + q;
        int e1 = i + 4 + q;
        int ec0 = (e0 < hi) ? e0 : hi - 1;         // in-bounds (loop => hi>lo)
        int ec1 = (e1 < hi) ? e1 : hi - 1;
        unsigned p0 = edata[ec0];                  // coalesced, L2-hot
        unsigned p1 = edata[ec1];
        float w0 = (e0 < hi) ? __uint_as_float((p0 & 0x7FFFu) << 16) : 0.f;
        float w1 = (e1 < hi) ? __uint_as_float((p1 & 0x7FFFu) << 16) : 0.f;
        const uint2* r0 = (const uint2*)(g32 + (size_t)(p0 >> 15) * (D / 2));
        const uint2* r1 = (const uint2*)(g32 + (size_t)(p1 >> 15) * (D / 2));
        uint2 u0 = r0[t];                          // 2 gathers in flight
        uint2 u1 = r1[t];
        acc.x += w0 * __uint_as_float(u0.x << 16);
        acc.y += w0 * __uint_as_float(u0.x & 0xFFFF0000u);
        acc.z += w0 * __uint_as_float(u0.y << 16);
        acc.w += w0 * __uint_as_float(u0.y & 0xFFFF0000u);
        sum += w0;
        acc.x += w1 * __uint_as_float(u1.x << 16);
        acc.y += w1 * __uint_as_float(u1.x & 0xFFFF0000u);
        acc.z += w1 * __uint_as_float(u1.y << 16);
        acc.w += w1 * __uint_as_float(u1.y & 0xFFFF0000u);
        sum += w1;
    }
    // combine the 4 groups (each lane t holds partials for feats 4t..4t+3)
    #pragma unroll
    for (int mm = 16; mm <= 32; mm <<= 1) {
        acc.x += __shfl_xor(acc.x, mm, 64);
        acc.y += __shfl_xor(acc.y, mm, 64);
        acc.z += __shfl_xor(acc.z, mm, 64);
        acc.w += __shfl_xor(acc.w, mm, 64);
        sum   += __shfl_xor(sum,   mm, 64);
    }
    if (hi > lo && q == 0) {                       // 16 lanes: float4 each
        float inv = 1.f / sum;
        float4* orow = (float4*)(out + (size_t)v * D);
        float4 c = orow[t];
        c.x += acc.x * inv; c.y += acc.y * inv;
        c.z += acc.z * inv; c.w += acc.w * inv;
        orow[t] = c;
    }
    // zero-degree nodes: reference gives h_neigh = 0 -> out keeps self part
}

// ---------------------------------------------------------------------------
extern "C" void kernel_launch(void* const* d_in, const int* in_sizes, int n_in,
                              void* d_out, int out_size, void* d_ws, size_t ws_size,
                              hipStream_t stream) {
    const float* feat    = (const float*)d_in[0];
    const float* rel     = (const float*)d_in[1];
    const float* W_self  = (const float*)d_in[2];
    const float* b_self  = (const float*)d_in[3];
    const float* W_neigh = (const float*)d_in[4];
    const float* b_neigh = (const float*)d_in[5];
    const float* attn_e  = (const float*)d_in[6];
    const int*   src     = (const int*)d_in[7];
    const int*   dst     = (const int*)d_in[8];
    float* out = (float*)d_out;

    // workspace layout (~34 MB)
    uint2* binned = (uint2*)d_ws;                               // 14.6 MB
    __hip_bfloat16* g = (__hip_bfloat16*)(binned + (size_t)NBUCK * BUCKET_CAP); // 12.8 MB
    unsigned* edata = (unsigned*)((char*)g + (size_t)N_NODES * D * 2);  // 6.4 MB
    int* offsets = (int*)(edata + N_EDGES);                     // [N+1]
    int* bucket_cursor = offsets + N_NODES + 1;                 // [NBUCK]
    int* bucket_base   = bucket_cursor + NBUCK;                 // [NBUCK]

    hipMemsetAsync(bucket_cursor, 0, NBUCK * sizeof(int), stream);

    binning_kernel<<<(N_EDGES + P1_EPB - 1) / P1_EPB, P1_T, 0, stream>>>(
        (const float2*)rel, attn_e, src, dst, bucket_cursor, binned);
    bucket_scan_kernel<<<1, 512, 0, stream>>>(bucket_cursor, bucket_base);
    csr_kernel<<<NBUCK, 512, 0, stream>>>(
        bucket_cursor, bucket_base, binned, offsets, edata);
    gemm_fused_kernel<<<(N_NODES + 63) / 64, 512, 0, stream>>>(
        feat, W_self, W_neigh, b_self, b_neigh, out, g);
    aggregate_kernel<<<N_NODES / 4, 256, 0, stream>>>(
        (const uint*)g, edata, offsets, out);
}